// Round 13
// baseline (177.726 us; speedup 1.0000x reference)
//
#include <hip/hip_runtime.h>
#include <cmath>

#define NUM_CLS 58

typedef _Float16 v8h __attribute__((ext_vector_type(8)));
typedef float v4f __attribute__((ext_vector_type(4)));
union HU { v8h h; uint4 u; };

// ---------------- merged prep: binarize w1/w2/w3/w4 + pack w0 MFMA B-fragments ----------------
// blocks 0..1151 -> w1, 1152..2303 -> w2, 2304..3455 -> w3, 3456..3583 -> w4,
// 3584..3591 -> B-frags: nt = id-3584; lane holds B[k=(lane>>4)*8+j][n=nt*16+(lane&15)]
__global__ void prep_all(const float* __restrict__ w0, const float* __restrict__ w1,
                         const float* __restrict__ w2, const float* __restrict__ w3,
                         const float* __restrict__ w4,
                         unsigned long long* __restrict__ wb1, unsigned long long* __restrict__ wb2,
                         unsigned long long* __restrict__ wb3, unsigned long long* __restrict__ wb4,
                         _Float16* __restrict__ bsig) {
    int id = blockIdx.x, lane = threadIdx.x;
    if (id < 3456) {
        const float* w = id < 1152 ? w1 : (id < 2304 ? w2 : w3);
        unsigned long long* o = id < 1152 ? wb1 : (id < 2304 ? wb2 : wb3);
        int item = id % 1152;
        int oc = item / 9, k = item % 9;
        const float* base = w + (size_t)oc * 1152 + k;   // element ic at base[ic*9]
        unsigned long long b0 = __ballot(base[lane * 9] >= 0.f);
        unsigned long long b1 = __ballot(base[(lane + 64) * 9] >= 0.f);
        if (lane == 0) { o[item * 2] = b0; o[item * 2 + 1] = b1; }
    } else if (id < 3584) {
        int oc = id - 3456;
        unsigned long long b0 = __ballot(w4[oc * 128 + lane] >= 0.f);
        unsigned long long b1 = __ballot(w4[oc * 128 + lane + 64] >= 0.f);
        if (lane == 0) { wb4[oc * 2] = b0; wb4[oc * 2 + 1] = b1; }
    } else {
        int nt = id - 3584;                 // 0..7
        int n = nt * 16 + (lane & 15);
        int k0 = (lane >> 4) * 8;
#pragma unroll
        for (int j = 0; j < 8; j++) {
            int k = k0 + j;
            float v = (k < 27) ? w0[n * 27 + k] : 0.f;
            bsig[(nt * 64 + lane) * 8 + j] = (_Float16)v;
        }
    }
}

// ---- one block per batch element ----
// HARD CONSTRAINT (r8-r12 evidence): allocator refuses >64 VGPRs for this kernel
// regardless of launch_bounds / amdgpu attrs — every phase must fit ~60 live regs.
__global__ __launch_bounds__(256, 4) void fused_net(
    const float* __restrict__ x, const float* __restrict__ w0,
    const _Float16* __restrict__ bsigG,
    const unsigned long long* __restrict__ wb1, const unsigned long long* __restrict__ wb2,
    const unsigned long long* __restrict__ wb3, const unsigned long long* __restrict__ wb4,
    const float* __restrict__ w5, float* __restrict__ out) {
    __shared__ float xs[3172];                 // image; row stride 33, channel stride 1057
    __shared__ uint4 bfrag[512];               // B sign-fragments, 8 nt x 64 lanes (8 KB)
    __shared__ alignas(16) unsigned long long bits1[450];  // [15*15][2]
    __shared__ alignas(16) unsigned long long bits2[72];
    __shared__ unsigned long long bits3[18];
    __shared__ unsigned long long bits4[2];
    __shared__ float r_s[128];
    __shared__ float l_s[NUM_CLS];
    __shared__ float e_s[NUM_CLS];
    __shared__ unsigned int qcnt;
    __shared__ unsigned int queue[1536];

    int b = blockIdx.x;
    int tid = threadIdx.x;
    int lane = tid & 63, wave = tid >> 6;

    // ================= phase 0: conv0 via f16 MFMA (pool-ordered im2col) =================
    // im2col row m' = p*4 + window  =>  each lane's 4 C-regs are one pooled pixel's
    // 2x2 window set for one oc: pool = OR over own regs, pack = 1 ballot per nt.
    {
        const float* xb = x + (size_t)b * 3072;
        for (int i = tid; i < 3072; i += 256) {
            int c = i >> 10, rem = i & 1023;
            xs[c * 1057 + (rem >> 5) * 33 + (rem & 31)] = xb[i];   // padded, coalesced
        }
        const uint4* bs4 = (const uint4*)bsigG;
        for (int i = tid; i < 512; i += 256) bfrag[i] = bs4[i];
        if (tid == 0) qcnt = 0;

        // per-lane A-gather offsets: k = k0+j -> (c,ky,kx); padded coords
        int k0 = (lane >> 4) * 8;
        int offj[8];
#pragma unroll
        for (int j = 0; j < 8; j++) {
            int k = k0 + j;
            int c = k / 9, r = (k % 9) / 3, q = k % 3;
            offj[j] = c * 1057 + r * 33 + q;
        }
        unsigned short* b1u16 = (unsigned short*)bits1;
        __syncthreads();

        for (int mt = wave; mt < 57; mt += 4) {   // M = 225*4 = 900 -> 57 tiles
            int mg = mt * 16 + (lane & 15);       // A row this lane supplies
            int me = mg < 900 ? mg : 899;         // pad rows read junk, discarded
            int p = me >> 2, win = me & 3;
            int py = p / 15, px = p - py * 15;
            int base = (py * 2 + (win >> 1)) * 33 + px * 2 + (win & 1);
            v8h a;
#pragma unroll
            for (int j = 0; j < 8; j++) {
                float v = (k0 + j < 27) ? xs[base + offj[j]] : 0.f;
                a[j] = (_Float16)v;
            }
            HU ua; ua.h = a;                      // |A| for the error-bound MFMA
            ua.u.x &= 0x7FFF7FFFu; ua.u.y &= 0x7FFF7FFFu;
            ua.u.z &= 0x7FFF7FFFu; ua.u.w &= 0x7FFF7FFFu;
            int myp = mt * 4 + (lane >> 4);       // pooled pixel of this lane's C-regs
#pragma unroll
            for (int nt = 0; nt < 8; nt++) {
                HU bs; bs.u = bfrag[nt * 64 + lane];
                HU ba; ba.u.x = bs.u.x & 0x7FFF7FFFu; ba.u.y = bs.u.y & 0x7FFF7FFFu;
                       ba.u.z = bs.u.z & 0x7FFF7FFFu; ba.u.w = bs.u.w & 0x7FFF7FFFu;
                v4f s  = __builtin_amdgcn_mfma_f32_16x16x32_f16(a,    bs.h, (v4f){0.f,0.f,0.f,0.f}, 0, 0, 0);
                v4f sa = __builtin_amdgcn_mfma_f32_16x16x32_f16(ua.h, ba.h, (v4f){0.f,0.f,0.f,0.f}, 0, 0, 0);
                bool pos = false; unsigned int fm = 0;
#pragma unroll
                for (int reg = 0; reg < 4; reg++) {
                    float bd = fmaf(sa[reg], 1.1e-3f, 1e-5f);   // rigorous f16-rounding bound
                    pos |= (s[reg] >= bd);                       // certain positive
                    fm  |= (fabsf(s[reg]) < bd) ? (1u << reg) : 0u;  // uncertain (win=reg)
                }
                unsigned long long mk = __ballot(pos);
                if ((lane & 15) == 0 && myp < 225)
                    b1u16[myp * 8 + nt] = (unsigned short)(mk >> (lane & 48));
                if (!pos && fm && myp < 225) {    // unresolved -> exact f64 later
                    unsigned int qi = atomicAdd(&qcnt, 1u);
                    if (qi < 1536) queue[qi] = (unsigned)myp | ((unsigned)(nt * 16 + (lane & 15)) << 8) | (fm << 16);
                }
            }
        }
        __syncthreads();
        // ---- drain queue: exact f64 signs for uncertain values ----
        unsigned int nq = qcnt < 1536u ? qcnt : 1536u;
        for (unsigned int i = tid; i < nq; i += 256) {
            unsigned int e = queue[i];
            int p = e & 255; int oc = (e >> 8) & 255; unsigned int fm = (e >> 16) & 15u;
            int py = p / 15, px = p - py * 15;
            bool pos = false;
#pragma unroll
            for (int win = 0; win < 4; win++) {
                if (!(fm & (1u << win))) continue;
                int base = (py * 2 + (win >> 1)) * 33 + px * 2 + (win & 1);
                double sd = 0.0;
#pragma unroll
                for (int k = 0; k < 27; k++) {
                    int c = k / 9, r = (k % 9) / 3, q = k % 3;
                    sd += (double)xs[base + c * 1057 + r * 33 + q] * (double)w0[oc * 27 + k];
                }
                pos |= (sd >= 0.0);
            }
            if (pos) atomicOr(&bits1[p * 2 + (oc >> 6)], 1ull << (oc & 63));
        }
    }
    __syncthreads();

    int wave2 = tid >> 6, half = wave2 & 1, pair = wave2 >> 1;
    int oc = half * 64 + lane;

    // ================= phase 1: binconv1 (15->13) + maxpool2 (->6) =================
    // row-wise, col-streamed: wave owns output rows {pair, pair+2, pair+4}; per row
    // two half-passes of 3 outputs; ONE ulonglong2 column live at a time (fits 64 VGPR).
    {
        unsigned long long wr[18];
#pragma unroll
        for (int j = 0; j < 18; j++) wr[j] = wb1[oc * 18 + j];
        const ulonglong2* b1v = (const ulonglong2*)bits1;
        for (int py = pair; py < 6; py += 2) {
#pragma unroll
            for (int h = 0; h < 2; h++) {
                int P[12];                        // [px(3)][dy(2)][dx(2)]
#pragma unroll
                for (int i = 0; i < 12; i++) P[i] = 0;
#pragma unroll
                for (int yy = 0; yy < 4; yy++) {
                    int rb = (2 * py + yy) * 15 + h * 6;
#pragma unroll
                    for (int c = 0; c < 8; c++) {
                        ulonglong2 Q = b1v[rb + c];
#pragma unroll
                        for (int dy = 0; dy < 2; dy++) {
                            int ky = yy - dy;
                            if (ky < 0 || ky > 2) continue;
#pragma unroll
                            for (int kx = 0; kx < 3; kx++)
#pragma unroll
                                for (int px = 0; px < 3; px++)
#pragma unroll
                                    for (int dx = 0; dx < 2; dx++)
                                        if (2 * px + dx + kx == c)
                                            P[px * 4 + dy * 2 + dx] +=
                                                __popcll(Q.x ^ wr[(ky * 3 + kx) * 2]) +
                                                __popcll(Q.y ^ wr[(ky * 3 + kx) * 2 + 1]);
                        }
                    }
                }
#pragma unroll
                for (int px = 0; px < 3; px++) {
                    bool pos = (P[px * 4] <= 576) | (P[px * 4 + 1] <= 576) |
                               (P[px * 4 + 2] <= 576) | (P[px * 4 + 3] <= 576);
                    unsigned long long m = __ballot(pos);
                    if (lane == 0) bits2[(py * 6 + h * 3 + px) * 2 + half] = m;
                }
            }
        }
    }
    __syncthreads();

    // ================= phase 2: binconv2 (6->4) + maxpool(2,s1) (->3) =================
    {
        unsigned long long wr[18];
#pragma unroll
        for (int j = 0; j < 18; j++) wr[j] = wb2[oc * 18 + j];
        const ulonglong2* b2v = (const ulonglong2*)bits2;
        for (int p = pair; p < 9; p += 2) {
            int py = p / 3, px = p % 3;
            bool pos = false;
#pragma unroll
            for (int dy = 0; dy < 2; dy++)
#pragma unroll
                for (int dx = 0; dx < 2; dx++) {
                    int P = 0;
#pragma unroll
                    for (int ky = 0; ky < 3; ky++)
#pragma unroll
                        for (int kx = 0; kx < 3; kx++) {
                            ulonglong2 q = b2v[(py + dy + ky) * 6 + (px + dx + kx)];
                            P += __popcll(q.x ^ wr[(ky * 3 + kx) * 2]);
                            P += __popcll(q.y ^ wr[(ky * 3 + kx) * 2 + 1]);
                        }
                    pos |= (P <= 576);
                }
            unsigned long long m = __ballot(pos);
            if (lane == 0) bits3[p * 2 + half] = m;
        }
    }
    __syncthreads();

    // ================= phase 3: binconv3 + binconv4 + relu + w5 + softmax =================
    if (tid < 128) {
        int P = 0;
#pragma unroll
        for (int k = 0; k < 9; k++) {
            P += __popcll(bits3[k * 2] ^ wb3[tid * 18 + k * 2]);
            P += __popcll(bits3[k * 2 + 1] ^ wb3[tid * 18 + k * 2 + 1]);
        }
        unsigned long long m = __ballot(P <= 576);
        if ((tid & 63) == 0) bits4[tid >> 6] = m;
    }
    __syncthreads();
    if (tid < 128) {
        unsigned long long i0 = bits4[0], i1 = bits4[1];
        int v = 128 - 2 * (int)(__popcll(i0 ^ wb4[tid * 2]) + __popcll(i1 ^ wb4[tid * 2 + 1]));
        r_s[tid] = v > 0 ? (float)v : 0.f;   // relu
    }
    __syncthreads();
    if (tid < NUM_CLS) {
        float l = 0.f;
#pragma unroll 8
        for (int k = 0; k < 128; k++) l = fmaf(w5[tid * 128 + k], r_s[k], l);
        l_s[tid] = l;
    }
    __syncthreads();
    if (tid < NUM_CLS) {
        float mx = -1e30f;
        for (int k = 0; k < NUM_CLS; k++) mx = fmaxf(mx, l_s[k]);
        e_s[tid] = expf(l_s[tid] - mx);
    }
    __syncthreads();
    if (tid < NUM_CLS) {
        float sum = 0.f;
        for (int k = 0; k < NUM_CLS; k++) sum += e_s[k];
        out[(size_t)b * NUM_CLS + tid] = e_s[tid] / sum;
    }
}

extern "C" void kernel_launch(void* const* d_in, const int* in_sizes, int n_in,
                              void* d_out, int out_size, void* d_ws, size_t ws_size,
                              hipStream_t stream) {
    const float* x  = (const float*)d_in[0];
    const float* w0 = (const float*)d_in[1];
    const float* w1 = (const float*)d_in[2];
    const float* w2 = (const float*)d_in[3];
    const float* w3 = (const float*)d_in[4];
    const float* w4 = (const float*)d_in[5];
    const float* w5 = (const float*)d_in[6];
    float* out = (float*)d_out;

    int B = in_sizes[0] / 3072;   // 1024

    size_t off = 0;
    auto carve = [&](size_t bytes) {
        void* p = (char*)d_ws + off;
        off += (bytes + 255) & ~(size_t)255;
        return p;
    };
    unsigned long long* wb1 = (unsigned long long*)carve(1152 * 2 * 8);
    unsigned long long* wb2 = (unsigned long long*)carve(1152 * 2 * 8);
    unsigned long long* wb3 = (unsigned long long*)carve(1152 * 2 * 8);
    unsigned long long* wb4 = (unsigned long long*)carve(128 * 2 * 8);
    _Float16* bsig = (_Float16*)carve(8 * 64 * 8 * 2);   // MFMA B-frags (signed)
    (void)ws_size; (void)n_in; (void)out_size;

    prep_all<<<3592, 64, 0, stream>>>(w0, w1, w2, w3, w4, wb1, wb2, wb3, wb4, bsig);
    fused_net<<<B, 256, 0, stream>>>(x, w0, bsig, wb1, wb2, wb3, wb4, w5, out);
}

// Round 14
// 172.252 us; speedup vs baseline: 1.0318x; 1.0318x over previous
//
#include <hip/hip_runtime.h>
#include <cmath>

#define NUM_CLS 58

typedef _Float16 v8h __attribute__((ext_vector_type(8)));
typedef float v4f __attribute__((ext_vector_type(4)));
union HU { v8h h; uint4 u; };

// ---------------- merged prep: binarize w1/w2/w3/w4 + pack w0 MFMA B-fragments ----------------
// blocks 0..1151 -> w1, 1152..2303 -> w2, 2304..3455 -> w3, 3456..3583 -> w4,
// 3584..3591 -> B-frags: nt = id-3584; lane holds B[k=(lane>>4)*8+j][n=nt*16+(lane&15)]
__global__ void prep_all(const float* __restrict__ w0, const float* __restrict__ w1,
                         const float* __restrict__ w2, const float* __restrict__ w3,
                         const float* __restrict__ w4,
                         unsigned long long* __restrict__ wb1, unsigned long long* __restrict__ wb2,
                         unsigned long long* __restrict__ wb3, unsigned long long* __restrict__ wb4,
                         _Float16* __restrict__ bsig) {
    int id = blockIdx.x, lane = threadIdx.x;
    if (id < 3456) {
        const float* w = id < 1152 ? w1 : (id < 2304 ? w2 : w3);
        unsigned long long* o = id < 1152 ? wb1 : (id < 2304 ? wb2 : wb3);
        int item = id % 1152;
        int oc = item / 9, k = item % 9;
        const float* base = w + (size_t)oc * 1152 + k;   // element ic at base[ic*9]
        unsigned long long b0 = __ballot(base[lane * 9] >= 0.f);
        unsigned long long b1 = __ballot(base[(lane + 64) * 9] >= 0.f);
        if (lane == 0) { o[item * 2] = b0; o[item * 2 + 1] = b1; }
    } else if (id < 3584) {
        int oc = id - 3456;
        unsigned long long b0 = __ballot(w4[oc * 128 + lane] >= 0.f);
        unsigned long long b1 = __ballot(w4[oc * 128 + lane + 64] >= 0.f);
        if (lane == 0) { wb4[oc * 2] = b0; wb4[oc * 2 + 1] = b1; }
    } else {
        int nt = id - 3584;                 // 0..7
        int n = nt * 16 + (lane & 15);
        int k0 = (lane >> 4) * 8;
#pragma unroll
        for (int j = 0; j < 8; j++) {
            int k = k0 + j;
            float v = (k < 27) ? w0[n * 27 + k] : 0.f;
            bsig[(nt * 64 + lane) * 8 + j] = (_Float16)v;
        }
    }
}

// ---- one block per batch element ----
// Structure = round 10 verbatim (the only spill-free MFMA variant: WRITE_SIZE
// 256 KB, 110 us). Changes: xs bank-padding (index-only) + queue 1536->512
// (LDS 32.7->28.7 KB => 5 blocks/CU). Do NOT grow any phase's live set:
// allocator caps this kernel at 64 VGPRs and spills ~24 MB/dispatch if exceeded
// (r11-r13 evidence).
__global__ __launch_bounds__(256, 4) void fused_net(
    const float* __restrict__ x, const float* __restrict__ w0,
    const _Float16* __restrict__ bsigG,
    const unsigned long long* __restrict__ wb1, const unsigned long long* __restrict__ wb2,
    const unsigned long long* __restrict__ wb3, const unsigned long long* __restrict__ wb4,
    const float* __restrict__ w5, float* __restrict__ out) {
    __shared__ float xs[3172];                 // image; row stride 33, channel stride 1057
    __shared__ uint4 bfrag[512];               // B sign-fragments, 8 nt x 64 lanes (8 KB)
    __shared__ alignas(16) unsigned long long bits1[450];  // [15*15][2]
    __shared__ alignas(16) unsigned long long bits2[72];
    __shared__ unsigned long long bits3[18];
    __shared__ unsigned long long bits4[2];
    __shared__ float r_s[128];
    __shared__ float l_s[NUM_CLS];
    __shared__ float e_s[NUM_CLS];
    __shared__ unsigned int qcnt;
    __shared__ unsigned int queue[512];

    int b = blockIdx.x;
    int tid = threadIdx.x;
    int lane = tid & 63, wave = tid >> 6;

    // ================= phase 0: conv0 via f16 MFMA (pool-ordered im2col) =================
    // im2col row m' = p*4 + window  =>  each lane's 4 C-regs are one pooled pixel's
    // 2x2 window set for one oc: pool = OR over own regs, pack = 1 ballot per nt.
    {
        const float* xb = x + (size_t)b * 3072;
        for (int i = tid; i < 3072; i += 256) {
            int c = i >> 10, rem = i & 1023;
            xs[c * 1057 + (rem >> 5) * 33 + (rem & 31)] = xb[i];   // padded, coalesced
        }
        const uint4* bs4 = (const uint4*)bsigG;
        for (int i = tid; i < 512; i += 256) bfrag[i] = bs4[i];
        if (tid == 0) qcnt = 0;

        // per-lane A-gather offsets: k = k0+j -> (c,ky,kx); padded coords
        int k0 = (lane >> 4) * 8;
        int offj[8];
#pragma unroll
        for (int j = 0; j < 8; j++) {
            int k = k0 + j;
            int c = k / 9, r = (k % 9) / 3, q = k % 3;
            offj[j] = c * 1057 + r * 33 + q;
        }
        unsigned short* b1u16 = (unsigned short*)bits1;
        __syncthreads();

        for (int mt = wave; mt < 57; mt += 4) {   // M = 225*4 = 900 -> 57 tiles
            int mg = mt * 16 + (lane & 15);       // A row this lane supplies
            int me = mg < 900 ? mg : 899;         // pad rows read junk, discarded
            int p = me >> 2, win = me & 3;
            int py = p / 15, px = p - py * 15;
            int base = (py * 2 + (win >> 1)) * 33 + px * 2 + (win & 1);
            v8h a;
#pragma unroll
            for (int j = 0; j < 8; j++) {
                float v = (k0 + j < 27) ? xs[base + offj[j]] : 0.f;
                a[j] = (_Float16)v;
            }
            HU ua; ua.h = a;                      // |A| for the error-bound MFMA
            ua.u.x &= 0x7FFF7FFFu; ua.u.y &= 0x7FFF7FFFu;
            ua.u.z &= 0x7FFF7FFFu; ua.u.w &= 0x7FFF7FFFu;
            int myp = mt * 4 + (lane >> 4);       // pooled pixel of this lane's C-regs
#pragma unroll
            for (int nt = 0; nt < 8; nt++) {
                HU bs; bs.u = bfrag[nt * 64 + lane];
                HU ba; ba.u.x = bs.u.x & 0x7FFF7FFFu; ba.u.y = bs.u.y & 0x7FFF7FFFu;
                       ba.u.z = bs.u.z & 0x7FFF7FFFu; ba.u.w = bs.u.w & 0x7FFF7FFFu;
                v4f s  = __builtin_amdgcn_mfma_f32_16x16x32_f16(a,    bs.h, (v4f){0.f,0.f,0.f,0.f}, 0, 0, 0);
                v4f sa = __builtin_amdgcn_mfma_f32_16x16x32_f16(ua.h, ba.h, (v4f){0.f,0.f,0.f,0.f}, 0, 0, 0);
                bool pos = false; unsigned int fm = 0;
#pragma unroll
                for (int reg = 0; reg < 4; reg++) {
                    float bd = fmaf(sa[reg], 1.1e-3f, 1e-5f);   // rigorous f16-rounding bound
                    pos |= (s[reg] >= bd);                       // certain positive
                    fm  |= (fabsf(s[reg]) < bd) ? (1u << reg) : 0u;  // uncertain (win=reg)
                }
                unsigned long long mk = __ballot(pos);
                if ((lane & 15) == 0 && myp < 225)
                    b1u16[myp * 8 + nt] = (unsigned short)(mk >> (lane & 48));
                if (!pos && fm && myp < 225) {    // unresolved -> exact f64 later
                    unsigned int qi = atomicAdd(&qcnt, 1u);
                    if (qi < 512) queue[qi] = (unsigned)myp | ((unsigned)(nt * 16 + (lane & 15)) << 8) | (fm << 16);
                }
            }
        }
        __syncthreads();
        // ---- drain queue: exact f64 signs for uncertain values ----
        unsigned int nq = qcnt < 512u ? qcnt : 512u;
        for (unsigned int i = tid; i < nq; i += 256) {
            unsigned int e = queue[i];
            int p = e & 255; int oc = (e >> 8) & 255; unsigned int fm = (e >> 16) & 15u;
            int py = p / 15, px = p - py * 15;
            bool pos = false;
#pragma unroll
            for (int win = 0; win < 4; win++) {
                if (!(fm & (1u << win))) continue;
                int base = (py * 2 + (win >> 1)) * 33 + px * 2 + (win & 1);
                double sd = 0.0;
#pragma unroll
                for (int k = 0; k < 27; k++) {
                    int c = k / 9, r = (k % 9) / 3, q = k % 3;
                    sd += (double)xs[base + c * 1057 + r * 33 + q] * (double)w0[oc * 27 + k];
                }
                pos |= (sd >= 0.0);
            }
            if (pos) atomicOr(&bits1[p * 2 + (oc >> 6)], 1ull << (oc & 63));
        }
    }
    __syncthreads();

    int wave2 = tid >> 6, half = wave2 & 1, pair = wave2 >> 1;
    int oc = half * 64 + lane;

    // ================= phase 1: binconv1 (15->13) + maxpool2 (->6) =================
    // r10-exact: per 4x4-patch row load 4x ulonglong2 (b128), scatter taps into
    // 4 pool-window partial popcounts. Live ~60 VGPR, known spill-free.
    {
        unsigned long long wr[18];
#pragma unroll
        for (int j = 0; j < 18; j++) wr[j] = wb1[oc * 18 + j];
        const ulonglong2* b1v = (const ulonglong2*)bits1;
        for (int p = pair; p < 36; p += 2) {
            int py = p / 6, px = p % 6;
            int P0 = 0, P1 = 0, P2 = 0, P3 = 0;
#pragma unroll
            for (int yy = 0; yy < 4; yy++) {
                int rb = (2 * py + yy) * 15 + 2 * px;
                ulonglong2 q0 = b1v[rb];
                ulonglong2 q1 = b1v[rb + 1];
                ulonglong2 q2 = b1v[rb + 2];
                ulonglong2 q3 = b1v[rb + 3];
#pragma unroll
                for (int dy = 0; dy < 2; dy++) {
                    int ky = yy - dy;
                    if (ky < 0 || ky > 2) continue;
#pragma unroll
                    for (int kx = 0; kx < 3; kx++) {
                        ulonglong2 qa = kx == 0 ? q0 : (kx == 1 ? q1 : q2);
                        ulonglong2 qb = kx == 0 ? q1 : (kx == 1 ? q2 : q3);
                        int d0 = __popcll(qa.x ^ wr[(ky * 3 + kx) * 2]) +
                                 __popcll(qa.y ^ wr[(ky * 3 + kx) * 2 + 1]);
                        int d1 = __popcll(qb.x ^ wr[(ky * 3 + kx) * 2]) +
                                 __popcll(qb.y ^ wr[(ky * 3 + kx) * 2 + 1]);
                        if (dy == 0) { P0 += d0; P1 += d1; }
                        else         { P2 += d0; P3 += d1; }
                    }
                }
            }
            bool pos = (P0 <= 576) | (P1 <= 576) | (P2 <= 576) | (P3 <= 576);
            unsigned long long m = __ballot(pos);
            if (lane == 0) bits2[p * 2 + half] = m;
        }
    }
    __syncthreads();

    // ================= phase 2: binconv2 (6->4) + maxpool(2,s1) (->3) =================
    {
        unsigned long long wr[18];
#pragma unroll
        for (int j = 0; j < 18; j++) wr[j] = wb2[oc * 18 + j];
        const ulonglong2* b2v = (const ulonglong2*)bits2;
        for (int p = pair; p < 9; p += 2) {
            int py = p / 3, px = p % 3;
            bool pos = false;
#pragma unroll
            for (int dy = 0; dy < 2; dy++)
#pragma unroll
                for (int dx = 0; dx < 2; dx++) {
                    int P = 0;
#pragma unroll
                    for (int ky = 0; ky < 3; ky++)
#pragma unroll
                        for (int kx = 0; kx < 3; kx++) {
                            ulonglong2 q = b2v[(py + dy + ky) * 6 + (px + dx + kx)];
                            P += __popcll(q.x ^ wr[(ky * 3 + kx) * 2]);
                            P += __popcll(q.y ^ wr[(ky * 3 + kx) * 2 + 1]);
                        }
                    pos |= (P <= 576);
                }
            unsigned long long m = __ballot(pos);
            if (lane == 0) bits3[p * 2 + half] = m;
        }
    }
    __syncthreads();

    // ================= phase 3: binconv3 + binconv4 + relu + w5 + softmax =================
    if (tid < 128) {
        int P = 0;
#pragma unroll
        for (int k = 0; k < 9; k++) {
            P += __popcll(bits3[k * 2] ^ wb3[tid * 18 + k * 2]);
            P += __popcll(bits3[k * 2 + 1] ^ wb3[tid * 18 + k * 2 + 1]);
        }
        unsigned long long m = __ballot(P <= 576);
        if ((tid & 63) == 0) bits4[tid >> 6] = m;
    }
    __syncthreads();
    if (tid < 128) {
        unsigned long long i0 = bits4[0], i1 = bits4[1];
        int v = 128 - 2 * (int)(__popcll(i0 ^ wb4[tid * 2]) + __popcll(i1 ^ wb4[tid * 2 + 1]));
        r_s[tid] = v > 0 ? (float)v : 0.f;   // relu
    }
    __syncthreads();
    if (tid < NUM_CLS) {
        float l = 0.f;
#pragma unroll 8
        for (int k = 0; k < 128; k++) l = fmaf(w5[tid * 128 + k], r_s[k], l);
        l_s[tid] = l;
    }
    __syncthreads();
    if (tid < NUM_CLS) {
        float mx = -1e30f;
        for (int k = 0; k < NUM_CLS; k++) mx = fmaxf(mx, l_s[k]);
        e_s[tid] = expf(l_s[tid] - mx);
    }
    __syncthreads();
    if (tid < NUM_CLS) {
        float sum = 0.f;
        for (int k = 0; k < NUM_CLS; k++) sum += e_s[k];
        out[(size_t)b * NUM_CLS + tid] = e_s[tid] / sum;
    }
}

extern "C" void kernel_launch(void* const* d_in, const int* in_sizes, int n_in,
                              void* d_out, int out_size, void* d_ws, size_t ws_size,
                              hipStream_t stream) {
    const float* x  = (const float*)d_in[0];
    const float* w0 = (const float*)d_in[1];
    const float* w1 = (const float*)d_in[2];
    const float* w2 = (const float*)d_in[3];
    const float* w3 = (const float*)d_in[4];
    const float* w4 = (const float*)d_in[5];
    const float* w5 = (const float*)d_in[6];
    float* out = (float*)d_out;

    int B = in_sizes[0] / 3072;   // 1024

    size_t off = 0;
    auto carve = [&](size_t bytes) {
        void* p = (char*)d_ws + off;
        off += (bytes + 255) & ~(size_t)255;
        return p;
    };
    unsigned long long* wb1 = (unsigned long long*)carve(1152 * 2 * 8);
    unsigned long long* wb2 = (unsigned long long*)carve(1152 * 2 * 8);
    unsigned long long* wb3 = (unsigned long long*)carve(1152 * 2 * 8);
    unsigned long long* wb4 = (unsigned long long*)carve(128 * 2 * 8);
    _Float16* bsig = (_Float16*)carve(8 * 64 * 8 * 2);   // MFMA B-frags (signed)
    (void)ws_size; (void)n_in; (void)out_size;

    prep_all<<<3592, 64, 0, stream>>>(w0, w1, w2, w3, w4, wb1, wb2, wb3, wb4, bsig);
    fused_net<<<B, 256, 0, stream>>>(x, w0, bsig, wb1, wb2, wb3, wb4, w5, out);
}

// Round 15
// 168.520 us; speedup vs baseline: 1.0546x; 1.0221x over previous
//
#include <hip/hip_runtime.h>
#include <cmath>

#define NUM_CLS 58

typedef _Float16 v8h __attribute__((ext_vector_type(8)));
typedef float v4f __attribute__((ext_vector_type(4)));
union HU { v8h h; uint4 u; };

// ---------------- prep v2: 256-thread blocks, coalesced staging ----------------
// blocks 0..383   : per-oc binarize of w1/w2/w3 (layer=id>>7, oc=id&127)
// blocks 384..415 : w4 binarize (1 oc per wave)
// blocks 416..417 : w0 MFMA B-fragments (4 nt per block)
__global__ __launch_bounds__(256) void prep_all(
    const float* __restrict__ w0, const float* __restrict__ w1,
    const float* __restrict__ w2, const float* __restrict__ w3,
    const float* __restrict__ w4,
    unsigned long long* __restrict__ wb1, unsigned long long* __restrict__ wb2,
    unsigned long long* __restrict__ wb3, unsigned long long* __restrict__ wb4,
    _Float16* __restrict__ bsig) {
    int id = blockIdx.x, tid = threadIdx.x;
    int lane = tid & 63, wv = tid >> 6;
    if (id < 384) {
        int layer = id >> 7, oc = id & 127;
        const float* w = layer == 0 ? w1 : (layer == 1 ? w2 : w3);
        unsigned long long* o = layer == 0 ? wb1 : (layer == 1 ? wb2 : wb3);
        __shared__ float s[1152];
        const float* base = w + (size_t)oc * 1152;
        for (int i = tid; i < 1152; i += 256) s[i] = base[i];   // coalesced
        __syncthreads();
        for (int k = wv; k < 9; k += 4) {    // stride-9 LDS reads: 2-way banks, free
            unsigned long long b0 = __ballot(s[lane * 9 + k] >= 0.f);
            unsigned long long b1 = __ballot(s[(lane + 64) * 9 + k] >= 0.f);
            if (lane == 0) { o[(oc * 9 + k) * 2] = b0; o[(oc * 9 + k) * 2 + 1] = b1; }
        }
    } else if (id < 416) {
        int oc = (id - 384) * 4 + wv;        // 128 oc over 32 blocks x 4 waves
        unsigned long long b0 = __ballot(w4[oc * 128 + lane] >= 0.f);
        unsigned long long b1 = __ballot(w4[oc * 128 + lane + 64] >= 0.f);
        if (lane == 0) { wb4[oc * 2] = b0; wb4[oc * 2 + 1] = b1; }
    } else {
        int nt = (id - 416) * 4 + wv;        // 8 nt over 2 blocks x 4 waves
        int n = nt * 16 + (lane & 15);
        int k0 = (lane >> 4) * 8;
#pragma unroll
        for (int j = 0; j < 8; j++) {
            int k = k0 + j;
            float v = (k < 27) ? w0[n * 27 + k] : 0.f;
            bsig[(nt * 64 + lane) * 8 + j] = (_Float16)v;
        }
    }
}

// ---- one block per batch element ----
// Structure = round 14 verbatim (spill-free at the allocator's hard 64-VGPR cap;
// r11-r13: any larger live set spills ~24 MB/dispatch). DO NOT grow live sets.
__global__ __launch_bounds__(256, 4) void fused_net(
    const float* __restrict__ x, const float* __restrict__ w0,
    const _Float16* __restrict__ bsigG,
    const unsigned long long* __restrict__ wb1, const unsigned long long* __restrict__ wb2,
    const unsigned long long* __restrict__ wb3, const unsigned long long* __restrict__ wb4,
    const float* __restrict__ w5, float* __restrict__ out) {
    __shared__ float xs[3172];                 // image; row stride 33, channel stride 1057
    __shared__ uint4 bfrag[512];               // B sign-fragments, 8 nt x 64 lanes (8 KB)
    __shared__ alignas(16) unsigned long long bits1[450];  // [15*15][2]
    __shared__ alignas(16) unsigned long long bits2[72];
    __shared__ unsigned long long bits3[18];
    __shared__ unsigned long long bits4[2];
    __shared__ float r_s[128];
    __shared__ float l_s[NUM_CLS];
    __shared__ float e_s[NUM_CLS];
    __shared__ unsigned int qcnt;
    __shared__ unsigned int queue[512];

    int b = blockIdx.x;
    int tid = threadIdx.x;
    int lane = tid & 63, wave = tid >> 6;

    // ================= phase 0: conv0 via f16 MFMA (pool-ordered im2col) =================
    {
        const float* xb = x + (size_t)b * 3072;
        for (int i = tid; i < 3072; i += 256) {
            int c = i >> 10, rem = i & 1023;
            xs[c * 1057 + (rem >> 5) * 33 + (rem & 31)] = xb[i];   // padded, coalesced
        }
        const uint4* bs4 = (const uint4*)bsigG;
        for (int i = tid; i < 512; i += 256) bfrag[i] = bs4[i];
        if (tid == 0) qcnt = 0;

        int k0 = (lane >> 4) * 8;
        int offj[8];
#pragma unroll
        for (int j = 0; j < 8; j++) {
            int k = k0 + j;
            int c = k / 9, r = (k % 9) / 3, q = k % 3;
            offj[j] = c * 1057 + r * 33 + q;
        }
        unsigned short* b1u16 = (unsigned short*)bits1;
        __syncthreads();

        for (int mt = wave; mt < 57; mt += 4) {   // M = 225*4 = 900 -> 57 tiles
            int mg = mt * 16 + (lane & 15);
            int me = mg < 900 ? mg : 899;
            int p = me >> 2, win = me & 3;
            int py = p / 15, px = p - py * 15;
            int base = (py * 2 + (win >> 1)) * 33 + px * 2 + (win & 1);
            v8h a;
#pragma unroll
            for (int j = 0; j < 8; j++) {
                float v = (k0 + j < 27) ? xs[base + offj[j]] : 0.f;
                a[j] = (_Float16)v;
            }
            HU ua; ua.h = a;
            ua.u.x &= 0x7FFF7FFFu; ua.u.y &= 0x7FFF7FFFu;
            ua.u.z &= 0x7FFF7FFFu; ua.u.w &= 0x7FFF7FFFu;
            int myp = mt * 4 + (lane >> 4);
#pragma unroll
            for (int nt = 0; nt < 8; nt++) {
                HU bs; bs.u = bfrag[nt * 64 + lane];
                HU ba; ba.u.x = bs.u.x & 0x7FFF7FFFu; ba.u.y = bs.u.y & 0x7FFF7FFFu;
                       ba.u.z = bs.u.z & 0x7FFF7FFFu; ba.u.w = bs.u.w & 0x7FFF7FFFu;
                v4f s  = __builtin_amdgcn_mfma_f32_16x16x32_f16(a,    bs.h, (v4f){0.f,0.f,0.f,0.f}, 0, 0, 0);
                v4f sa = __builtin_amdgcn_mfma_f32_16x16x32_f16(ua.h, ba.h, (v4f){0.f,0.f,0.f,0.f}, 0, 0, 0);
                bool pos = false; unsigned int fm = 0;
#pragma unroll
                for (int reg = 0; reg < 4; reg++) {
                    float bd = fmaf(sa[reg], 1.1e-3f, 1e-5f);   // rigorous f16-rounding bound
                    pos |= (s[reg] >= bd);
                    fm  |= (fabsf(s[reg]) < bd) ? (1u << reg) : 0u;
                }
                unsigned long long mk = __ballot(pos);
                if ((lane & 15) == 0 && myp < 225)
                    b1u16[myp * 8 + nt] = (unsigned short)(mk >> (lane & 48));
                if (!pos && fm && myp < 225) {
                    unsigned int qi = atomicAdd(&qcnt, 1u);
                    if (qi < 512) queue[qi] = (unsigned)myp | ((unsigned)(nt * 16 + (lane & 15)) << 8) | (fm << 16);
                }
            }
        }
        __syncthreads();
        // ---- drain queue: exact f64 signs for uncertain values ----
        unsigned int nq = qcnt < 512u ? qcnt : 512u;
        for (unsigned int i = tid; i < nq; i += 256) {
            unsigned int e = queue[i];
            int p = e & 255; int oc = (e >> 8) & 255; unsigned int fm = (e >> 16) & 15u;
            int py = p / 15, px = p - py * 15;
            bool pos = false;
#pragma unroll
            for (int win = 0; win < 4; win++) {
                if (!(fm & (1u << win))) continue;
                int base = (py * 2 + (win >> 1)) * 33 + px * 2 + (win & 1);
                double sd = 0.0;
#pragma unroll
                for (int k = 0; k < 27; k++) {
                    int c = k / 9, r = (k % 9) / 3, q = k % 3;
                    sd += (double)xs[base + c * 1057 + r * 33 + q] * (double)w0[oc * 27 + k];
                }
                pos |= (sd >= 0.0);
            }
            if (pos) atomicOr(&bits1[p * 2 + (oc >> 6)], 1ull << (oc & 63));
        }
    }
    __syncthreads();

    int wave2 = tid >> 6, half = wave2 & 1, pair = wave2 >> 1;
    int oc = half * 64 + lane;

    // ================= phase 1: binconv1 (15->13) + maxpool2 (->6) =================
    {
        unsigned long long wr[18];
#pragma unroll
        for (int j = 0; j < 18; j++) wr[j] = wb1[oc * 18 + j];
        const ulonglong2* b1v = (const ulonglong2*)bits1;
        for (int p = pair; p < 36; p += 2) {
            int py = p / 6, px = p % 6;
            int P0 = 0, P1 = 0, P2 = 0, P3 = 0;
#pragma unroll
            for (int yy = 0; yy < 4; yy++) {
                int rb = (2 * py + yy) * 15 + 2 * px;
                ulonglong2 q0 = b1v[rb];
                ulonglong2 q1 = b1v[rb + 1];
                ulonglong2 q2 = b1v[rb + 2];
                ulonglong2 q3 = b1v[rb + 3];
#pragma unroll
                for (int dy = 0; dy < 2; dy++) {
                    int ky = yy - dy;
                    if (ky < 0 || ky > 2) continue;
#pragma unroll
                    for (int kx = 0; kx < 3; kx++) {
                        ulonglong2 qa = kx == 0 ? q0 : (kx == 1 ? q1 : q2);
                        ulonglong2 qb = kx == 0 ? q1 : (kx == 1 ? q2 : q3);
                        int d0 = __popcll(qa.x ^ wr[(ky * 3 + kx) * 2]) +
                                 __popcll(qa.y ^ wr[(ky * 3 + kx) * 2 + 1]);
                        int d1 = __popcll(qb.x ^ wr[(ky * 3 + kx) * 2]) +
                                 __popcll(qb.y ^ wr[(ky * 3 + kx) * 2 + 1]);
                        if (dy == 0) { P0 += d0; P1 += d1; }
                        else         { P2 += d0; P3 += d1; }
                    }
                }
            }
            bool pos = (P0 <= 576) | (P1 <= 576) | (P2 <= 576) | (P3 <= 576);
            unsigned long long m = __ballot(pos);
            if (lane == 0) bits2[p * 2 + half] = m;
        }
    }
    __syncthreads();

    // ================= phase 2: binconv2 (6->4) + maxpool(2,s1) (->3) =================
    {
        unsigned long long wr[18];
#pragma unroll
        for (int j = 0; j < 18; j++) wr[j] = wb2[oc * 18 + j];
        const ulonglong2* b2v = (const ulonglong2*)bits2;
        for (int p = pair; p < 9; p += 2) {
            int py = p / 3, px = p % 3;
            bool pos = false;
#pragma unroll
            for (int dy = 0; dy < 2; dy++)
#pragma unroll
                for (int dx = 0; dx < 2; dx++) {
                    int P = 0;
#pragma unroll
                    for (int ky = 0; ky < 3; ky++)
#pragma unroll
                        for (int kx = 0; kx < 3; kx++) {
                            ulonglong2 q = b2v[(py + dy + ky) * 6 + (px + dx + kx)];
                            P += __popcll(q.x ^ wr[(ky * 3 + kx) * 2]);
                            P += __popcll(q.y ^ wr[(ky * 3 + kx) * 2 + 1]);
                        }
                    pos |= (P <= 576);
                }
            unsigned long long m = __ballot(pos);
            if (lane == 0) bits3[p * 2 + half] = m;
        }
    }
    __syncthreads();

    // ================= phase 3: binconv3 + binconv4 + relu + w5 + softmax =================
    if (tid < 128) {
        int P = 0;
#pragma unroll
        for (int k = 0; k < 9; k++) {
            P += __popcll(bits3[k * 2] ^ wb3[tid * 18 + k * 2]);
            P += __popcll(bits3[k * 2 + 1] ^ wb3[tid * 18 + k * 2 + 1]);
        }
        unsigned long long m = __ballot(P <= 576);
        if ((tid & 63) == 0) bits4[tid >> 6] = m;
    }
    __syncthreads();
    if (tid < 128) {
        unsigned long long i0 = bits4[0], i1 = bits4[1];
        int v = 128 - 2 * (int)(__popcll(i0 ^ wb4[tid * 2]) + __popcll(i1 ^ wb4[tid * 2 + 1]));
        r_s[tid] = v > 0 ? (float)v : 0.f;   // relu
    }
    __syncthreads();
    if (tid < NUM_CLS) {
        float l = 0.f;
#pragma unroll 8
        for (int k = 0; k < 128; k++) l = fmaf(w5[tid * 128 + k], r_s[k], l);
        l_s[tid] = l;
    }
    __syncthreads();
    if (tid < NUM_CLS) {
        float mx = -1e30f;
        for (int k = 0; k < NUM_CLS; k++) mx = fmaxf(mx, l_s[k]);
        e_s[tid] = expf(l_s[tid] - mx);
    }
    __syncthreads();
    if (tid < NUM_CLS) {
        float sum = 0.f;
        for (int k = 0; k < NUM_CLS; k++) sum += e_s[k];
        out[(size_t)b * NUM_CLS + tid] = e_s[tid] / sum;
    }
}

extern "C" void kernel_launch(void* const* d_in, const int* in_sizes, int n_in,
                              void* d_out, int out_size, void* d_ws, size_t ws_size,
                              hipStream_t stream) {
    const float* x  = (const float*)d_in[0];
    const float* w0 = (const float*)d_in[1];
    const float* w1 = (const float*)d_in[2];
    const float* w2 = (const float*)d_in[3];
    const float* w3 = (const float*)d_in[4];
    const float* w4 = (const float*)d_in[5];
    const float* w5 = (const float*)d_in[6];
    float* out = (float*)d_out;

    int B = in_sizes[0] / 3072;   // 1024

    size_t off = 0;
    auto carve = [&](size_t bytes) {
        void* p = (char*)d_ws + off;
        off += (bytes + 255) & ~(size_t)255;
        return p;
    };
    unsigned long long* wb1 = (unsigned long long*)carve(1152 * 2 * 8);
    unsigned long long* wb2 = (unsigned long long*)carve(1152 * 2 * 8);
    unsigned long long* wb3 = (unsigned long long*)carve(1152 * 2 * 8);
    unsigned long long* wb4 = (unsigned long long*)carve(128 * 2 * 8);
    _Float16* bsig = (_Float16*)carve(8 * 64 * 8 * 2);   // MFMA B-frags (signed)
    (void)ws_size; (void)n_in; (void)out_size;

    prep_all<<<418, 256, 0, stream>>>(w0, w1, w2, w3, w4, wb1, wb2, wb3, wb4, bsig);
    fused_net<<<B, 256, 0, stream>>>(x, w0, bsig, wb1, wb2, wb3, wb4, w5, out);
}

// Round 16
// 165.535 us; speedup vs baseline: 1.0736x; 1.0180x over previous
//
#include <hip/hip_runtime.h>
#include <cmath>

#define NUM_CLS 58

typedef _Float16 v8h __attribute__((ext_vector_type(8)));
typedef float v4f __attribute__((ext_vector_type(4)));
union HU { v8h h; uint4 u; };

// ---------------- prep v2: 256-thread blocks, coalesced staging ----------------
// blocks 0..383   : per-oc binarize of w1/w2/w3 (layer=id>>7, oc=id&127)
// blocks 384..415 : w4 binarize (1 oc per wave)
// blocks 416..417 : w0 MFMA B-fragments (4 nt per block)
__global__ __launch_bounds__(256) void prep_all(
    const float* __restrict__ w0, const float* __restrict__ w1,
    const float* __restrict__ w2, const float* __restrict__ w3,
    const float* __restrict__ w4,
    unsigned long long* __restrict__ wb1, unsigned long long* __restrict__ wb2,
    unsigned long long* __restrict__ wb3, unsigned long long* __restrict__ wb4,
    _Float16* __restrict__ bsig) {
    int id = blockIdx.x, tid = threadIdx.x;
    int lane = tid & 63, wv = tid >> 6;
    if (id < 384) {
        int layer = id >> 7, oc = id & 127;
        const float* w = layer == 0 ? w1 : (layer == 1 ? w2 : w3);
        unsigned long long* o = layer == 0 ? wb1 : (layer == 1 ? wb2 : wb3);
        __shared__ float s[1152];
        const float* base = w + (size_t)oc * 1152;
        for (int i = tid; i < 1152; i += 256) s[i] = base[i];   // coalesced
        __syncthreads();
        for (int k = wv; k < 9; k += 4) {    // stride-9 LDS reads: 2-way banks, free
            unsigned long long b0 = __ballot(s[lane * 9 + k] >= 0.f);
            unsigned long long b1 = __ballot(s[(lane + 64) * 9 + k] >= 0.f);
            if (lane == 0) { o[(oc * 9 + k) * 2] = b0; o[(oc * 9 + k) * 2 + 1] = b1; }
        }
    } else if (id < 416) {
        int oc = (id - 384) * 4 + wv;        // 128 oc over 32 blocks x 4 waves
        unsigned long long b0 = __ballot(w4[oc * 128 + lane] >= 0.f);
        unsigned long long b1 = __ballot(w4[oc * 128 + lane + 64] >= 0.f);
        if (lane == 0) { wb4[oc * 2] = b0; wb4[oc * 2 + 1] = b1; }
    } else {
        int nt = (id - 416) * 4 + wv;        // 8 nt over 2 blocks x 4 waves
        int n = nt * 16 + (lane & 15);
        int k0 = (lane >> 4) * 8;
#pragma unroll
        for (int j = 0; j < 8; j++) {
            int k = k0 + j;
            float v = (k < 27) ? w0[n * 27 + k] : 0.f;
            bsig[(nt * 64 + lane) * 8 + j] = (_Float16)v;
        }
    }
}

// ---- one block per batch element ----
// Structure = round 15 except: xs staged as f16 (LDS 28.7K -> ~21K => 7 blocks/CU)
// and f64 fallback reads x from GLOBAL (rare). Allocator caps this kernel at
// 64 VGPRs and spills ~24 MB/dispatch if any phase's live set grows (r11-r13).
__global__ __launch_bounds__(256, 4) void fused_net(
    const float* __restrict__ x, const float* __restrict__ w0,
    const _Float16* __restrict__ bsigG,
    const unsigned long long* __restrict__ wb1, const unsigned long long* __restrict__ wb2,
    const unsigned long long* __restrict__ wb3, const unsigned long long* __restrict__ wb4,
    const float* __restrict__ w5, float* __restrict__ out) {
    __shared__ _Float16 xh[3172];              // image f16; row stride 33, chan stride 1057
    __shared__ uint4 bfrag[512];               // B sign-fragments, 8 nt x 64 lanes (8 KB)
    __shared__ alignas(16) unsigned long long bits1[450];  // [15*15][2]
    __shared__ alignas(16) unsigned long long bits2[72];
    __shared__ unsigned long long bits3[18];
    __shared__ unsigned long long bits4[2];
    __shared__ float r_s[128];
    __shared__ float l_s[NUM_CLS];
    __shared__ float e_s[NUM_CLS];
    __shared__ unsigned int qcnt;
    __shared__ unsigned int queue[256];

    int b = blockIdx.x;
    int tid = threadIdx.x;
    int lane = tid & 63, wave = tid >> 6;
    const float* xb = x + (size_t)b * 3072;

    // ================= phase 0: conv0 via f16 MFMA (pool-ordered im2col) =================
    {
        for (int i = tid; i < 3072; i += 256) {
            int c = i >> 10, rem = i & 1023;
            xh[c * 1057 + (rem >> 5) * 33 + (rem & 31)] = (_Float16)xb[i];  // cvt at staging
        }
        const uint4* bs4 = (const uint4*)bsigG;
        for (int i = tid; i < 512; i += 256) bfrag[i] = bs4[i];
        if (tid == 0) qcnt = 0;

        int k0 = (lane >> 4) * 8;
        int offj[8];
#pragma unroll
        for (int j = 0; j < 8; j++) {
            int k = k0 + j;
            int c = k / 9, r = (k % 9) / 3, q = k % 3;
            offj[j] = c * 1057 + r * 33 + q;
        }
        unsigned short* b1u16 = (unsigned short*)bits1;
        __syncthreads();

        for (int mt = wave; mt < 57; mt += 4) {   // M = 225*4 = 900 -> 57 tiles
            int mg = mt * 16 + (lane & 15);
            int me = mg < 900 ? mg : 899;
            int p = me >> 2, win = me & 3;
            int py = p / 15, px = p - py * 15;
            int base = (py * 2 + (win >> 1)) * 33 + px * 2 + (win & 1);
            v8h a;
#pragma unroll
            for (int j = 0; j < 8; j++)
                a[j] = (k0 + j < 27) ? xh[base + offj[j]] : (_Float16)0.f;
            HU ua; ua.h = a;                      // |A| for the error-bound MFMA
            ua.u.x &= 0x7FFF7FFFu; ua.u.y &= 0x7FFF7FFFu;
            ua.u.z &= 0x7FFF7FFFu; ua.u.w &= 0x7FFF7FFFu;
            int myp = mt * 4 + (lane >> 4);
#pragma unroll
            for (int nt = 0; nt < 8; nt++) {
                HU bs; bs.u = bfrag[nt * 64 + lane];
                HU ba; ba.u.x = bs.u.x & 0x7FFF7FFFu; ba.u.y = bs.u.y & 0x7FFF7FFFu;
                       ba.u.z = bs.u.z & 0x7FFF7FFFu; ba.u.w = bs.u.w & 0x7FFF7FFFu;
                v4f s  = __builtin_amdgcn_mfma_f32_16x16x32_f16(a,    bs.h, (v4f){0.f,0.f,0.f,0.f}, 0, 0, 0);
                v4f sa = __builtin_amdgcn_mfma_f32_16x16x32_f16(ua.h, ba.h, (v4f){0.f,0.f,0.f,0.f}, 0, 0, 0);
                bool pos = false; unsigned int fm = 0;
#pragma unroll
                for (int reg = 0; reg < 4; reg++) {
                    float bd = fmaf(sa[reg], 1.1e-3f, 1e-5f);   // rigorous f16-rounding bound
                    pos |= (s[reg] >= bd);                       // certain positive
                    fm  |= (fabsf(s[reg]) < bd) ? (1u << reg) : 0u;  // uncertain (win=reg)
                }
                unsigned long long mk = __ballot(pos);
                if ((lane & 15) == 0 && myp < 225)
                    b1u16[myp * 8 + nt] = (unsigned short)(mk >> (lane & 48));
                if (!pos && fm && myp < 225) {    // unresolved -> exact f64 later
                    unsigned int qi = atomicAdd(&qcnt, 1u);
                    if (qi < 256) queue[qi] = (unsigned)myp | ((unsigned)(nt * 16 + (lane & 15)) << 8) | (fm << 16);
                }
            }
        }
        __syncthreads();
        // ---- drain queue: exact f64 signs from GLOBAL f32 x (rare, L1/L2-warm) ----
        unsigned int nq = qcnt < 256u ? qcnt : 256u;
        for (unsigned int i = tid; i < nq; i += 256) {
            unsigned int e = queue[i];
            int p = e & 255; int oc = (e >> 8) & 255; unsigned int fm = (e >> 16) & 15u;
            int py = p / 15, px = p - py * 15;
            bool pos = false;
#pragma unroll
            for (int win = 0; win < 4; win++) {
                if (!(fm & (1u << win))) continue;
                int base = (py * 2 + (win >> 1)) * 32 + px * 2 + (win & 1);
                double sd = 0.0;
#pragma unroll
                for (int k = 0; k < 27; k++) {
                    int c = k / 9, r = (k % 9) / 3, q = k % 3;
                    sd += (double)xb[base + c * 1024 + r * 32 + q] * (double)w0[oc * 27 + k];
                }
                pos |= (sd >= 0.0);
            }
            if (pos) atomicOr(&bits1[p * 2 + (oc >> 6)], 1ull << (oc & 63));
        }
    }
    __syncthreads();

    int wave2 = tid >> 6, half = wave2 & 1, pair = wave2 >> 1;
    int oc = half * 64 + lane;

    // ================= phase 1: binconv1 (15->13) + maxpool2 (->6) =================
    {
        unsigned long long wr[18];
#pragma unroll
        for (int j = 0; j < 18; j++) wr[j] = wb1[oc * 18 + j];
        const ulonglong2* b1v = (const ulonglong2*)bits1;
        for (int p = pair; p < 36; p += 2) {
            int py = p / 6, px = p % 6;
            int P0 = 0, P1 = 0, P2 = 0, P3 = 0;
#pragma unroll
            for (int yy = 0; yy < 4; yy++) {
                int rb = (2 * py + yy) * 15 + 2 * px;
                ulonglong2 q0 = b1v[rb];
                ulonglong2 q1 = b1v[rb + 1];
                ulonglong2 q2 = b1v[rb + 2];
                ulonglong2 q3 = b1v[rb + 3];
#pragma unroll
                for (int dy = 0; dy < 2; dy++) {
                    int ky = yy - dy;
                    if (ky < 0 || ky > 2) continue;
#pragma unroll
                    for (int kx = 0; kx < 3; kx++) {
                        ulonglong2 qa = kx == 0 ? q0 : (kx == 1 ? q1 : q2);
                        ulonglong2 qb = kx == 0 ? q1 : (kx == 1 ? q2 : q3);
                        int d0 = __popcll(qa.x ^ wr[(ky * 3 + kx) * 2]) +
                                 __popcll(qa.y ^ wr[(ky * 3 + kx) * 2 + 1]);
                        int d1 = __popcll(qb.x ^ wr[(ky * 3 + kx) * 2]) +
                                 __popcll(qb.y ^ wr[(ky * 3 + kx) * 2 + 1]);
                        if (dy == 0) { P0 += d0; P1 += d1; }
                        else         { P2 += d0; P3 += d1; }
                    }
                }
            }
            bool pos = (P0 <= 576) | (P1 <= 576) | (P2 <= 576) | (P3 <= 576);
            unsigned long long m = __ballot(pos);
            if (lane == 0) bits2[p * 2 + half] = m;
        }
    }
    __syncthreads();

    // ================= phase 2: binconv2 (6->4) + maxpool(2,s1) (->3) =================
    {
        unsigned long long wr[18];
#pragma unroll
        for (int j = 0; j < 18; j++) wr[j] = wb2[oc * 18 + j];
        const ulonglong2* b2v = (const ulonglong2*)bits2;
        for (int p = pair; p < 9; p += 2) {
            int py = p / 3, px = p % 3;
            bool pos = false;
#pragma unroll
            for (int dy = 0; dy < 2; dy++)
#pragma unroll
                for (int dx = 0; dx < 2; dx++) {
                    int P = 0;
#pragma unroll
                    for (int ky = 0; ky < 3; ky++)
#pragma unroll
                        for (int kx = 0; kx < 3; kx++) {
                            ulonglong2 q = b2v[(py + dy + ky) * 6 + (px + dx + kx)];
                            P += __popcll(q.x ^ wr[(ky * 3 + kx) * 2]);
                            P += __popcll(q.y ^ wr[(ky * 3 + kx) * 2 + 1]);
                        }
                    pos |= (P <= 576);
                }
            unsigned long long m = __ballot(pos);
            if (lane == 0) bits3[p * 2 + half] = m;
        }
    }
    __syncthreads();

    // ================= phase 3: binconv3 + binconv4 + relu + w5 + softmax =================
    if (tid < 128) {
        int P = 0;
#pragma unroll
        for (int k = 0; k < 9; k++) {
            P += __popcll(bits3[k * 2] ^ wb3[tid * 18 + k * 2]);
            P += __popcll(bits3[k * 2 + 1] ^ wb3[tid * 18 + k * 2 + 1]);
        }
        unsigned long long m = __ballot(P <= 576);
        if ((tid & 63) == 0) bits4[tid >> 6] = m;
    }
    __syncthreads();
    if (tid < 128) {
        unsigned long long i0 = bits4[0], i1 = bits4[1];
        int v = 128 - 2 * (int)(__popcll(i0 ^ wb4[tid * 2]) + __popcll(i1 ^ wb4[tid * 2 + 1]));
        r_s[tid] = v > 0 ? (float)v : 0.f;   // relu
    }
    __syncthreads();
    if (tid < NUM_CLS) {
        float l = 0.f;
#pragma unroll 8
        for (int k = 0; k < 128; k++) l = fmaf(w5[tid * 128 + k], r_s[k], l);
        l_s[tid] = l;
    }
    __syncthreads();
    if (tid < NUM_CLS) {
        float mx = -1e30f;
        for (int k = 0; k < NUM_CLS; k++) mx = fmaxf(mx, l_s[k]);
        e_s[tid] = expf(l_s[tid] - mx);
    }
    __syncthreads();
    if (tid < NUM_CLS) {
        float sum = 0.f;
        for (int k = 0; k < NUM_CLS; k++) sum += e_s[k];
        out[(size_t)b * NUM_CLS + tid] = e_s[tid] / sum;
    }
}

extern "C" void kernel_launch(void* const* d_in, const int* in_sizes, int n_in,
                              void* d_out, int out_size, void* d_ws, size_t ws_size,
                              hipStream_t stream) {
    const float* x  = (const float*)d_in[0];
    const float* w0 = (const float*)d_in[1];
    const float* w1 = (const float*)d_in[2];
    const float* w2 = (const float*)d_in[3];
    const float* w3 = (const float*)d_in[4];
    const float* w4 = (const float*)d_in[5];
    const float* w5 = (const float*)d_in[6];
    float* out = (float*)d_out;

    int B = in_sizes[0] / 3072;   // 1024

    size_t off = 0;
    auto carve = [&](size_t bytes) {
        void* p = (char*)d_ws + off;
        off += (bytes + 255) & ~(size_t)255;
        return p;
    };
    unsigned long long* wb1 = (unsigned long long*)carve(1152 * 2 * 8);
    unsigned long long* wb2 = (unsigned long long*)carve(1152 * 2 * 8);
    unsigned long long* wb3 = (unsigned long long*)carve(1152 * 2 * 8);
    unsigned long long* wb4 = (unsigned long long*)carve(128 * 2 * 8);
    _Float16* bsig = (_Float16*)carve(8 * 64 * 8 * 2);   // MFMA B-frags (signed)
    (void)ws_size; (void)n_in; (void)out_size;

    prep_all<<<418, 256, 0, stream>>>(w0, w1, w2, w3, w4, wb1, wb2, wb3, wb4, bsig);
    fused_net<<<B, 256, 0, stream>>>(x, w0, bsig, wb1, wb2, wb3, wb4, w5, out);
}

// Round 17
// 159.870 us; speedup vs baseline: 1.1117x; 1.0354x over previous
//
#include <hip/hip_runtime.h>
#include <cmath>

#define NUM_CLS 58

typedef _Float16 v8h __attribute__((ext_vector_type(8)));
typedef float v4f __attribute__((ext_vector_type(4)));
union HU { v8h h; uint4 u; };

// ---------------- prep v3: 256-thread blocks, coalesced staging ----------------
// blocks 0..383   : per-oc binarize of w1/w2/w3 (layer=id>>7, oc=id&127)
// blocks 384..415 : w4 binarize (1 oc per wave)
// blocks 416..417 : w0 MFMA B-fragments, signed + abs (4 nt per block)
__global__ __launch_bounds__(256) void prep_all(
    const float* __restrict__ w0, const float* __restrict__ w1,
    const float* __restrict__ w2, const float* __restrict__ w3,
    const float* __restrict__ w4,
    unsigned long long* __restrict__ wb1, unsigned long long* __restrict__ wb2,
    unsigned long long* __restrict__ wb3, unsigned long long* __restrict__ wb4,
    _Float16* __restrict__ bsig, _Float16* __restrict__ babs) {
    int id = blockIdx.x, tid = threadIdx.x;
    int lane = tid & 63, wv = tid >> 6;
    if (id < 384) {
        int layer = id >> 7, oc = id & 127;
        const float* w = layer == 0 ? w1 : (layer == 1 ? w2 : w3);
        unsigned long long* o = layer == 0 ? wb1 : (layer == 1 ? wb2 : wb3);
        __shared__ float s[1152];
        const float* base = w + (size_t)oc * 1152;
        for (int i = tid; i < 1152; i += 256) s[i] = base[i];   // coalesced
        __syncthreads();
        for (int k = wv; k < 9; k += 4) {    // stride-9 LDS reads: 2-way banks, free
            unsigned long long b0 = __ballot(s[lane * 9 + k] >= 0.f);
            unsigned long long b1 = __ballot(s[(lane + 64) * 9 + k] >= 0.f);
            if (lane == 0) { o[(oc * 9 + k) * 2] = b0; o[(oc * 9 + k) * 2 + 1] = b1; }
        }
    } else if (id < 416) {
        int oc = (id - 384) * 4 + wv;        // 128 oc over 32 blocks x 4 waves
        unsigned long long b0 = __ballot(w4[oc * 128 + lane] >= 0.f);
        unsigned long long b1 = __ballot(w4[oc * 128 + lane + 64] >= 0.f);
        if (lane == 0) { wb4[oc * 2] = b0; wb4[oc * 2 + 1] = b1; }
    } else {
        int nt = (id - 416) * 4 + wv;        // 8 nt over 2 blocks x 4 waves
        int n = nt * 16 + (lane & 15);
        int k0 = (lane >> 4) * 8;
#pragma unroll
        for (int j = 0; j < 8; j++) {
            int k = k0 + j;
            float v = (k < 27) ? w0[n * 27 + k] : 0.f;
            bsig[(nt * 64 + lane) * 8 + j] = (_Float16)v;
            babs[(nt * 64 + lane) * 8 + j] = (_Float16)fabsf(v);
        }
    }
}

// ---- one block per batch element ----
// VALU-issue-bound at the allocator's hard 64-VGPR cap (r11-r13: bigger live
// sets spill ~24 MB/dispatch). Occupancy is grid-capped (1024 blocks = 4/CU).
// This round: minimal-instruction sign logic (ballot-compares), |B| from LDS.
__global__ __launch_bounds__(256, 4) void fused_net(
    const float* __restrict__ x, const float* __restrict__ w0,
    const _Float16* __restrict__ bsigG, const _Float16* __restrict__ babsG,
    const unsigned long long* __restrict__ wb1, const unsigned long long* __restrict__ wb2,
    const unsigned long long* __restrict__ wb3, const unsigned long long* __restrict__ wb4,
    const float* __restrict__ w5, float* __restrict__ out) {
    __shared__ _Float16 xh[3172];              // image f16; row stride 33, chan stride 1057
    __shared__ uint4 bfrag[512];               // B sign-fragments (8 KB)
    __shared__ uint4 bfraga[512];              // |B| fragments (8 KB)
    __shared__ alignas(16) unsigned long long bits1[450];  // [15*15][2]
    __shared__ alignas(16) unsigned long long bits2[72];
    __shared__ unsigned long long bits3[18];
    __shared__ unsigned long long bits4[2];
    __shared__ float r_s[128];
    __shared__ float l_s[NUM_CLS];
    __shared__ float e_s[NUM_CLS];
    __shared__ unsigned int qcnt;
    __shared__ unsigned int queue[256];

    int b = blockIdx.x;
    int tid = threadIdx.x;
    int lane = tid & 63, wave = tid >> 6;
    const float* xb = x + (size_t)b * 3072;

    // ================= phase 0: conv0 via f16 MFMA (pool-ordered im2col) =================
    {
        for (int i = tid; i < 3072; i += 256) {
            int c = i >> 10, rem = i & 1023;
            xh[c * 1057 + (rem >> 5) * 33 + (rem & 31)] = (_Float16)xb[i];  // cvt at staging
        }
        const uint4* bs4 = (const uint4*)bsigG;
        const uint4* ba4 = (const uint4*)babsG;
        for (int i = tid; i < 512; i += 256) { bfrag[i] = bs4[i]; bfraga[i] = ba4[i]; }
        if (tid == 0) qcnt = 0;

        int k0 = (lane >> 4) * 8;
        int offj[8];
#pragma unroll
        for (int j = 0; j < 8; j++) {
            int k = k0 + j;
            int c = k / 9, r = (k % 9) / 3, q = k % 3;
            offj[j] = c * 1057 + r * 33 + q;
        }
        unsigned short* b1u16 = (unsigned short*)bits1;
        __syncthreads();

        for (int mt = wave; mt < 57; mt += 4) {   // M = 225*4 = 900 -> 57 tiles
            int mg = mt * 16 + (lane & 15);
            int me = mg < 900 ? mg : 899;
            int p = me >> 2, win = me & 3;
            int py = p / 15, px = p - py * 15;
            int base = (py * 2 + (win >> 1)) * 33 + px * 2 + (win & 1);
            v8h a;
#pragma unroll
            for (int j = 0; j < 8; j++)
                a[j] = (k0 + j < 27) ? xh[base + offj[j]] : (_Float16)0.f;
            HU ua; ua.h = a;                      // |A| for the error-bound MFMA
            ua.u.x &= 0x7FFF7FFFu; ua.u.y &= 0x7FFF7FFFu;
            ua.u.z &= 0x7FFF7FFFu; ua.u.w &= 0x7FFF7FFFu;
            int myp = mt * 4 + (lane >> 4);
#pragma unroll
            for (int nt = 0; nt < 8; nt++) {
                HU bs; bs.u = bfrag[nt * 64 + lane];
                HU ba; ba.u = bfraga[nt * 64 + lane];
                v4f s  = __builtin_amdgcn_mfma_f32_16x16x32_f16(a,    bs.h, (v4f){0.f,0.f,0.f,0.f}, 0, 0, 0);
                v4f sa = __builtin_amdgcn_mfma_f32_16x16x32_f16(ua.h, ba.h, (v4f){0.f,0.f,0.f,0.f}, 0, 0, 0);
                // rigorous f16-rounding bounds; sign logic as wave-mask ballots
                float bd0 = fmaf(sa[0], 1.1e-3f, 1e-5f);
                float bd1 = fmaf(sa[1], 1.1e-3f, 1e-5f);
                float bd2 = fmaf(sa[2], 1.1e-3f, 1e-5f);
                float bd3 = fmaf(sa[3], 1.1e-3f, 1e-5f);
                unsigned long long mkpos =
                    __ballot(s[0] >= bd0) | __ballot(s[1] >= bd1) |
                    __ballot(s[2] >= bd2) | __ballot(s[3] >= bd3);
                unsigned long long mkunc =
                    (__ballot(fabsf(s[0]) < bd0) | __ballot(fabsf(s[1]) < bd1) |
                     __ballot(fabsf(s[2]) < bd2) | __ballot(fabsf(s[3]) < bd3)) & ~mkpos;
                if ((lane & 15) == 0 && myp < 225)
                    b1u16[myp * 8 + nt] = (unsigned short)(mkpos >> (lane & 48));
                if (__builtin_expect(mkunc != 0ull, 0)) {
                    if (((mkunc >> lane) & 1ull) && myp < 225) {
                        unsigned int qi = atomicAdd(&qcnt, 1u);
                        if (qi < 256) queue[qi] = (unsigned)myp | ((unsigned)(nt * 16 + (lane & 15)) << 8);
                    }
                }
            }
        }
        __syncthreads();
        // ---- drain queue: exact f64 signs from GLOBAL f32 x (rare; all 4 windows) ----
        unsigned int nq = qcnt < 256u ? qcnt : 256u;
        for (unsigned int i = tid; i < nq; i += 256) {
            unsigned int e = queue[i];
            int p = e & 255; int oc = (e >> 8) & 255;
            int py = p / 15, px = p - py * 15;
            bool pos = false;
#pragma unroll
            for (int win = 0; win < 4; win++) {
                int base = (py * 2 + (win >> 1)) * 32 + px * 2 + (win & 1);
                double sd = 0.0;
#pragma unroll
                for (int k = 0; k < 27; k++) {
                    int c = k / 9, r = (k % 9) / 3, q = k % 3;
                    sd += (double)xb[base + c * 1024 + r * 32 + q] * (double)w0[oc * 27 + k];
                }
                pos |= (sd >= 0.0);
            }
            if (pos) atomicOr(&bits1[p * 2 + (oc >> 6)], 1ull << (oc & 63));
        }
    }
    __syncthreads();

    int wave2 = tid >> 6, half = wave2 & 1, pair = wave2 >> 1;
    int oc = half * 64 + lane;

    // ================= phase 1: binconv1 (15->13) + maxpool2 (->6) =================
    {
        unsigned long long wr[18];
#pragma unroll
        for (int j = 0; j < 18; j++) wr[j] = wb1[oc * 18 + j];
        const ulonglong2* b1v = (const ulonglong2*)bits1;
        for (int p = pair; p < 36; p += 2) {
            int py = p / 6, px = p % 6;
            int P0 = 0, P1 = 0, P2 = 0, P3 = 0;
#pragma unroll
            for (int yy = 0; yy < 4; yy++) {
                int rb = (2 * py + yy) * 15 + 2 * px;
                ulonglong2 q0 = b1v[rb];
                ulonglong2 q1 = b1v[rb + 1];
                ulonglong2 q2 = b1v[rb + 2];
                ulonglong2 q3 = b1v[rb + 3];
#pragma unroll
                for (int dy = 0; dy < 2; dy++) {
                    int ky = yy - dy;
                    if (ky < 0 || ky > 2) continue;
#pragma unroll
                    for (int kx = 0; kx < 3; kx++) {
                        ulonglong2 qa = kx == 0 ? q0 : (kx == 1 ? q1 : q2);
                        ulonglong2 qb = kx == 0 ? q1 : (kx == 1 ? q2 : q3);
                        int d0 = __popcll(qa.x ^ wr[(ky * 3 + kx) * 2]) +
                                 __popcll(qa.y ^ wr[(ky * 3 + kx) * 2 + 1]);
                        int d1 = __popcll(qb.x ^ wr[(ky * 3 + kx) * 2]) +
                                 __popcll(qb.y ^ wr[(ky * 3 + kx) * 2 + 1]);
                        if (dy == 0) { P0 += d0; P1 += d1; }
                        else         { P2 += d0; P3 += d1; }
                    }
                }
            }
            unsigned long long m = __ballot(P0 <= 576) | __ballot(P1 <= 576) |
                                   __ballot(P2 <= 576) | __ballot(P3 <= 576);
            if (lane == 0) bits2[p * 2 + half] = m;
        }
    }
    __syncthreads();

    // ================= phase 2: binconv2 (6->4) + maxpool(2,s1) (->3) =================
    {
        unsigned long long wr[18];
#pragma unroll
        for (int j = 0; j < 18; j++) wr[j] = wb2[oc * 18 + j];
        const ulonglong2* b2v = (const ulonglong2*)bits2;
        for (int p = pair; p < 9; p += 2) {
            int py = p / 3, px = p % 3;
            int P4[4];
#pragma unroll
            for (int dy = 0; dy < 2; dy++)
#pragma unroll
                for (int dx = 0; dx < 2; dx++) {
                    int P = 0;
#pragma unroll
                    for (int ky = 0; ky < 3; ky++)
#pragma unroll
                        for (int kx = 0; kx < 3; kx++) {
                            ulonglong2 q = b2v[(py + dy + ky) * 6 + (px + dx + kx)];
                            P += __popcll(q.x ^ wr[(ky * 3 + kx) * 2]);
                            P += __popcll(q.y ^ wr[(ky * 3 + kx) * 2 + 1]);
                        }
                    P4[dy * 2 + dx] = P;
                }
            unsigned long long m = __ballot(P4[0] <= 576) | __ballot(P4[1] <= 576) |
                                   __ballot(P4[2] <= 576) | __ballot(P4[3] <= 576);
            if (lane == 0) bits3[p * 2 + half] = m;
        }
    }
    __syncthreads();

    // ================= phase 3: binconv3 + binconv4 + relu + w5 + softmax =================
    if (tid < 128) {
        int P = 0;
#pragma unroll
        for (int k = 0; k < 9; k++) {
            P += __popcll(bits3[k * 2] ^ wb3[tid * 18 + k * 2]);
            P += __popcll(bits3[k * 2 + 1] ^ wb3[tid * 18 + k * 2 + 1]);
        }
        unsigned long long m = __ballot(P <= 576);
        if ((tid & 63) == 0) bits4[tid >> 6] = m;
    }
    __syncthreads();
    if (tid < 128) {
        unsigned long long i0 = bits4[0], i1 = bits4[1];
        int v = 128 - 2 * (int)(__popcll(i0 ^ wb4[tid * 2]) + __popcll(i1 ^ wb4[tid * 2 + 1]));
        r_s[tid] = v > 0 ? (float)v : 0.f;   // relu
    }
    __syncthreads();
    if (tid < NUM_CLS) {
        float l = 0.f;
#pragma unroll 8
        for (int k = 0; k < 128; k++) l = fmaf(w5[tid * 128 + k], r_s[k], l);
        l_s[tid] = l;
    }
    __syncthreads();
    if (tid < NUM_CLS) {
        float mx = -1e30f;
        for (int k = 0; k < NUM_CLS; k++) mx = fmaxf(mx, l_s[k]);
        e_s[tid] = expf(l_s[tid] - mx);
    }
    __syncthreads();
    if (tid < NUM_CLS) {
        float sum = 0.f;
        for (int k = 0; k < NUM_CLS; k++) sum += e_s[k];
        out[(size_t)b * NUM_CLS + tid] = e_s[tid] / sum;
    }
}

extern "C" void kernel_launch(void* const* d_in, const int* in_sizes, int n_in,
                              void* d_out, int out_size, void* d_ws, size_t ws_size,
                              hipStream_t stream) {
    const float* x  = (const float*)d_in[0];
    const float* w0 = (const float*)d_in[1];
    const float* w1 = (const float*)d_in[2];
    const float* w2 = (const float*)d_in[3];
    const float* w3 = (const float*)d_in[4];
    const float* w4 = (const float*)d_in[5];
    const float* w5 = (const float*)d_in[6];
    float* out = (float*)d_out;

    int B = in_sizes[0] / 3072;   // 1024

    size_t off = 0;
    auto carve = [&](size_t bytes) {
        void* p = (char*)d_ws + off;
        off += (bytes + 255) & ~(size_t)255;
        return p;
    };
    unsigned long long* wb1 = (unsigned long long*)carve(1152 * 2 * 8);
    unsigned long long* wb2 = (unsigned long long*)carve(1152 * 2 * 8);
    unsigned long long* wb3 = (unsigned long long*)carve(1152 * 2 * 8);
    unsigned long long* wb4 = (unsigned long long*)carve(128 * 2 * 8);
    _Float16* bsig = (_Float16*)carve(8 * 64 * 8 * 2);   // MFMA B-frags (signed)
    _Float16* babs = (_Float16*)carve(8 * 64 * 8 * 2);   // MFMA B-frags (abs)
    (void)ws_size; (void)n_in; (void)out_size;

    prep_all<<<418, 256, 0, stream>>>(w0, w1, w2, w3, w4, wb1, wb2, wb3, wb4, bsig, babs);
    fused_net<<<B, 256, 0, stream>>>(x, w0, bsig, babs, wb1, wb2, wb3, wb4, w5, out);
}